// Round 1
// baseline (969.701 us; speedup 1.0000x reference)
//
#include <hip/hip_runtime.h>

// Shapes (fixed by the reference):
// B=16, S=512, L=12, H=12, DH=64, D=768, M=13
// attn GEMM: A rows (b,s)=8192 x K=9216, W_O = [K=9216][N=768]

#define D_ 768
#define K_ 9216
#define ROWS_ 8192   // B*S
#define SPLITS 8
#define KSPLIT (K_ / SPLITS)   // 1152
#define BK 32
#define NT (KSPLIT / BK)       // 36

typedef __attribute__((ext_vector_type(8))) short short8;
typedef __attribute__((ext_vector_type(8))) unsigned short ushort8;
typedef __attribute__((ext_vector_type(4))) float f32x4;

typedef unsigned int __attribute__((address_space(1))) gu32;
typedef unsigned int __attribute__((address_space(3))) lu32;

__device__ __forceinline__ void async_copy16(const void* g, void* l) {
    __builtin_amdgcn_global_load_lds((const gu32*)g, (lu32*)l, 16, 0, 0);
}

// round-to-nearest-even f32 -> bf16 (finite inputs)
__device__ __forceinline__ unsigned short f2bf(float f) {
    union { float f; unsigned u; } a; a.f = f;
    unsigned r = a.u + 0x7FFF + ((a.u >> 16) & 1);
    return (unsigned short)(r >> 16);
}

// ---------------- K0: per-batch bias, parallel over d ----------------
__global__ __launch_bounds__(256) void bias_kernel(
    const float* __restrict__ mlp_mask, const float* __restrict__ attn_mask,
    const float* __restrict__ modal_mlp, const float* __restrict__ modal_att,
    const float* __restrict__ post_bias, float* __restrict__ bias) {
    int b = blockIdx.x;
    int d = blockIdx.y * 256 + threadIdx.x;
    float acc = 0.f;
    #pragma unroll
    for (int p = 0; p < 12; ++p) acc += post_bias[p * D_ + d];
    #pragma unroll
    for (int m = 0; m < 13; ++m)
        acc += (1.f - mlp_mask[b * 13 + m]) * modal_mlp[m * D_ + d];
    #pragma unroll 16
    for (int ph = 0; ph < 144; ++ph)
        acc += (1.f - attn_mask[b * 144 + ph]) * modal_att[ph * D_ + d];
    bias[b * D_ + d] = acc;
}

// ---------------- K1: transpose-convert W_O [9216,768] f32 -> Bt [768,9216] bf16 ----------------
__global__ __launch_bounds__(256) void transpose_wo(
    const float* __restrict__ W, unsigned short* __restrict__ Bt) {
    __shared__ float tile[32][33];
    int n0 = blockIdx.x * 32;
    int k0 = blockIdx.y * 32;
    int tx = threadIdx.x & 31, ty = threadIdx.x >> 5;
    #pragma unroll
    for (int i = 0; i < 4; ++i)
        tile[ty + 8 * i][tx] = W[(k0 + ty + 8 * i) * D_ + n0 + tx];
    __syncthreads();
    #pragma unroll
    for (int i = 0; i < 4; ++i)
        Bt[(n0 + ty + 8 * i) * K_ + k0 + tx] = f2bf(tile[tx][ty + 8 * i]);
}

// ---------------- K2: mask+convert attn_stack f32 -> A bf16, 8 elems/thread ----------------
__global__ __launch_bounds__(256) void conv_attn(
    const float* __restrict__ attn_stack, const float* __restrict__ attn_mask,
    unsigned short* __restrict__ A) {
    int i = (blockIdx.x * 256 + threadIdx.x) * 8;   // < 75.5M, fits int
    int row = i / K_;
    int k = i - row * K_;
    int b = row >> 9;
    float w = attn_mask[b * 144 + (k >> 6)];        // k 8-aligned: one (p,h) group
    float4 v0 = *(const float4*)&attn_stack[i];
    float4 v1 = *(const float4*)&attn_stack[i + 4];
    ushort8 o;
    o[0] = f2bf(v0.x * w); o[1] = f2bf(v0.y * w);
    o[2] = f2bf(v0.z * w); o[3] = f2bf(v0.w * w);
    o[4] = f2bf(v1.x * w); o[5] = f2bf(v1.y * w);
    o[6] = f2bf(v1.z * w); o[7] = f2bf(v1.w * w);
    *(ushort8*)&A[i] = o;
}

// ---------------- K3: out = bias + sum_m mlp_mask*mlp_stack ----------------
__global__ __launch_bounds__(256) void mlp_kernel(
    const float* __restrict__ mlp_stack, const float* __restrict__ mlp_mask,
    const float* __restrict__ bias, float* __restrict__ out) {
    int i4 = (blockIdx.x * 256 + threadIdx.x) * 4;
    int row = i4 / D_;
    int d = i4 - row * D_;
    int b = row >> 9;
    float4 acc = *(const float4*)&bias[b * D_ + d];
    const float* base = mlp_stack + (long)row * 13 * D_ + d;
    #pragma unroll
    for (int m = 0; m < 13; ++m) {
        float w = mlp_mask[b * 13 + m];
        float4 v = *(const float4*)&base[m * D_];
        acc.x += w * v.x; acc.y += w * v.y;
        acc.z += w * v.z; acc.w += w * v.w;
    }
    *(float4*)&out[i4] = acc;
}

// ---------------- K4: out += A[8192x9216] * Bt^T, split-K, bf16 MFMA ----------------
// 256x256 tile, BK=32, 8 waves in 4x2 (each wave 64 rows x 128 cols, 4x8 MFMA 16x16x32).
// Double-buffered LDS, single __syncthreads per K-step (stage issued EARLY so L3
// latency hides under MFMA). XCD-chunked block swizzle: each XCD's 32 resident
// blocks share one B-panel (L2) and one A K-chunk (L3).
// grid = 32 row-tiles * 3 col-tiles * SPLITS = 768 (1-D); atomic epilogue.
__global__ __launch_bounds__(512, 2) void gemm_attn(
    const short* __restrict__ A, const short* __restrict__ Bt,
    float* __restrict__ out) {
    __shared__ __align__(16) short As[2][256 * 32];
    __shared__ __align__(16) short Bs[2][256 * 32];

    // bijective XCD swizzle (768 % 8 == 0): XCD x runs logical ids [x*96, x*96+96)
    const int bid = (int)blockIdx.x;
    const int l = (bid & 7) * 96 + (bid >> 3);
    const int z = l / 96;                  // == bid & 7
    const int rem = l - z * 96;
    const int ytile = rem >> 5;            // 0..2
    const int xtile = rem & 31;            // 0..31

    const int tid = threadIdx.x;
    const int wave = tid >> 6, lane = tid & 63;
    const int row0 = xtile * 256;
    const int col0 = ytile * 256;
    const int kStart = z * KSPLIT;
    const int wr = (wave >> 1) * 64;       // 0,64,128,192
    const int wc = (wave & 1) * 128;       // 0,128

    f32x4 acc[4][8] = {};

    // staging: chunk c (16 rows x 64 B) ; lane -> rc=lane>>2 (row), x=lane&3 (granule)
    const int rc = lane >> 2;
    const int x = lane & 3;
    const int g = x ^ ((rc >> 1) & 3);     // XOR-swizzled 16B granule (bank-conflict-free reads)

    int a_off[2], b_off[2], lof[2];
    #pragma unroll
    for (int j = 0; j < 2; ++j) {
        int c = wave * 2 + j;              // chunks 0..15 cover 256 rows
        a_off[j] = (row0 + c * 16 + rc) * K_ + g * 8 + kStart;
        b_off[j] = (col0 + c * 16 + rc) * K_ + g * 8 + kStart;
        lof[j] = c * 1024;                 // bytes, wave-uniform
    }

    const int fr = lane & 15;
    const int q = lane >> 4;
    const int pos = q ^ ((fr >> 1) & 3);

    // prologue: stage tile 0 into buffer 0
    #pragma unroll
    for (int j = 0; j < 2; ++j) {
        async_copy16(A + a_off[j], (char*)As[0] + lof[j]);
        async_copy16(Bt + b_off[j], (char*)Bs[0] + lof[j]);
    }
    __syncthreads();

    int cur = 0;
    for (int t = 0; t < NT; ++t) {
        // issue NEXT tile's loads first — latency overlaps the MFMAs below
        if (t + 1 < NT) {
            const int k0 = (t + 1) * BK;
            #pragma unroll
            for (int j = 0; j < 2; ++j) {
                async_copy16(A + a_off[j] + k0, (char*)As[cur ^ 1] + lof[j]);
                async_copy16(Bt + b_off[j] + k0, (char*)Bs[cur ^ 1] + lof[j]);
            }
        }
        short8 af[4], bf[8];
        #pragma unroll
        for (int i = 0; i < 4; ++i)
            af[i] = *(const short8*)&As[cur][(wr + i * 16 + fr) * 32 + pos * 8];
        #pragma unroll
        for (int j = 0; j < 8; ++j)
            bf[j] = *(const short8*)&Bs[cur][(wc + j * 16 + fr) * 32 + pos * 8];
        #pragma unroll
        for (int i = 0; i < 4; ++i)
            #pragma unroll
            for (int j = 0; j < 8; ++j)
                acc[i][j] = __builtin_amdgcn_mfma_f32_16x16x32_bf16(
                    af[i], bf[j], acc[i][j], 0, 0, 0);
        // one barrier per K-step: drains this wave's vmcnt (next tile staged)
        // and lgkmcnt, then joins — next iter reads cur^1 safely.
        __syncthreads();
        cur ^= 1;
    }

    // epilogue: D row m = q*4+reg, col n = lane&15 ; atomic accumulate
    #pragma unroll
    for (int i = 0; i < 4; ++i) {
        int m = row0 + wr + i * 16 + q * 4;
        #pragma unroll
        for (int j = 0; j < 8; ++j) {
            int n = col0 + wc + j * 16 + fr;
            float* p = out + m * D_ + n;
            #pragma unroll
            for (int r = 0; r < 4; ++r)
                atomicAdd(p + r * D_, acc[i][j][r]);
        }
    }
}

extern "C" void kernel_launch(void* const* d_in, const int* in_sizes, int n_in,
                              void* d_out, int out_size, void* d_ws, size_t ws_size,
                              hipStream_t stream) {
    const float* mlp_stack  = (const float*)d_in[0];
    const float* attn_stack = (const float*)d_in[1];
    const float* mlp_mask   = (const float*)d_in[2];
    const float* attn_mask  = (const float*)d_in[3];
    const float* modal_mlp  = (const float*)d_in[4];
    const float* modal_att  = (const float*)d_in[5];
    const float* W_O        = (const float*)d_in[6];
    const float* post_bias  = (const float*)d_in[7];
    float* out = (float*)d_out;

    char* ws = (char*)d_ws;
    unsigned short* Abf = (unsigned short*)ws;                 // 150,994,944 B
    unsigned short* Btb = (unsigned short*)(ws + 150994944);   //  14,155,776 B
    float* bias = (float*)(ws + 150994944 + 14155776);         //      49,152 B

    bias_kernel<<<dim3(16, 3), 256, 0, stream>>>(mlp_mask, attn_mask, modal_mlp,
                                                 modal_att, post_bias, bias);
    transpose_wo<<<dim3(24, 288), 256, 0, stream>>>(W_O, Btb);
    conv_attn<<<36864, 256, 0, stream>>>(attn_stack, attn_mask, Abf);
    mlp_kernel<<<6144, 256, 0, stream>>>(mlp_stack, mlp_mask, bias, out);
    gemm_attn<<<768, 512, 0, stream>>>((const short*)Abf, (const short*)Btb, out);
}

// Round 2
// 941.755 us; speedup vs baseline: 1.0297x; 1.0297x over previous
//
#include <hip/hip_runtime.h>

// Shapes (fixed by the reference):
// B=16, S=512, L=12, H=12, DH=64, D=768, M=13
// attn GEMM: A rows (b,s)=8192 x K=9216, W_O = [K=9216][N=768]

#define D_ 768
#define K_ 9216
#define ROWS_ 8192   // B*S
#define SPLITS 8
#define KSPLIT (K_ / SPLITS)   // 1152
#define BK 32
#define NT (KSPLIT / BK)       // 36

typedef __attribute__((ext_vector_type(8))) short short8;
typedef __attribute__((ext_vector_type(8))) unsigned short ushort8;
typedef __attribute__((ext_vector_type(4))) float f32x4;

typedef unsigned int __attribute__((address_space(1))) gu32;
typedef unsigned int __attribute__((address_space(3))) lu32;

__device__ __forceinline__ void async_copy16(const void* g, void* l) {
    __builtin_amdgcn_global_load_lds((const gu32*)g, (lu32*)l, 16, 0, 0);
}

// round-to-nearest-even f32 -> bf16 (finite inputs)
__device__ __forceinline__ unsigned short f2bf(float f) {
    union { float f; unsigned u; } a; a.f = f;
    unsigned r = a.u + 0x7FFF + ((a.u >> 16) & 1);
    return (unsigned short)(r >> 16);
}

// ---------------- K0: per-batch bias, parallel over d ----------------
__global__ __launch_bounds__(256) void bias_kernel(
    const float* __restrict__ mlp_mask, const float* __restrict__ attn_mask,
    const float* __restrict__ modal_mlp, const float* __restrict__ modal_att,
    const float* __restrict__ post_bias, float* __restrict__ bias) {
    int b = blockIdx.x;
    int d = blockIdx.y * 256 + threadIdx.x;
    float acc = 0.f;
    #pragma unroll
    for (int p = 0; p < 12; ++p) acc += post_bias[p * D_ + d];
    #pragma unroll
    for (int m = 0; m < 13; ++m)
        acc += (1.f - mlp_mask[b * 13 + m]) * modal_mlp[m * D_ + d];
    #pragma unroll 16
    for (int ph = 0; ph < 144; ++ph)
        acc += (1.f - attn_mask[b * 144 + ph]) * modal_att[ph * D_ + d];
    bias[b * D_ + d] = acc;
}

// ---------------- K1: transpose-convert W_O [9216,768] f32 -> Bt [768,9216] bf16 ----------------
__global__ __launch_bounds__(256) void transpose_wo(
    const float* __restrict__ W, unsigned short* __restrict__ Bt) {
    __shared__ float tile[32][33];
    int n0 = blockIdx.x * 32;
    int k0 = blockIdx.y * 32;
    int tx = threadIdx.x & 31, ty = threadIdx.x >> 5;
    #pragma unroll
    for (int i = 0; i < 4; ++i)
        tile[ty + 8 * i][tx] = W[(k0 + ty + 8 * i) * D_ + n0 + tx];
    __syncthreads();
    #pragma unroll
    for (int i = 0; i < 4; ++i)
        Bt[(n0 + ty + 8 * i) * K_ + k0 + tx] = f2bf(tile[tx][ty + 8 * i]);
}

// ---------------- K2: mask+convert attn_stack f32 -> A bf16, 8 elems/thread ----------------
__global__ __launch_bounds__(256) void conv_attn(
    const float* __restrict__ attn_stack, const float* __restrict__ attn_mask,
    unsigned short* __restrict__ A) {
    int i = (blockIdx.x * 256 + threadIdx.x) * 8;   // < 75.5M, fits int
    int row = i / K_;
    int k = i - row * K_;
    int b = row >> 9;
    float w = attn_mask[b * 144 + (k >> 6)];        // k 8-aligned: one (p,h) group
    float4 v0 = *(const float4*)&attn_stack[i];
    float4 v1 = *(const float4*)&attn_stack[i + 4];
    ushort8 o;
    o[0] = f2bf(v0.x * w); o[1] = f2bf(v0.y * w);
    o[2] = f2bf(v0.z * w); o[3] = f2bf(v0.w * w);
    o[4] = f2bf(v1.x * w); o[5] = f2bf(v1.y * w);
    o[6] = f2bf(v1.z * w); o[7] = f2bf(v1.w * w);
    *(ushort8*)&A[i] = o;
}

// ---------------- K3: out = bias + sum_m mlp_mask*mlp_stack ----------------
__global__ __launch_bounds__(256) void mlp_kernel(
    const float* __restrict__ mlp_stack, const float* __restrict__ mlp_mask,
    const float* __restrict__ bias, float* __restrict__ out) {
    int i4 = (blockIdx.x * 256 + threadIdx.x) * 4;
    int row = i4 / D_;
    int d = i4 - row * D_;
    int b = row >> 9;
    float4 acc = *(const float4*)&bias[b * D_ + d];
    const float* base = mlp_stack + (long)row * 13 * D_ + d;
    #pragma unroll
    for (int m = 0; m < 13; ++m) {
        float w = mlp_mask[b * 13 + m];
        float4 v = *(const float4*)&base[m * D_];
        acc.x += w * v.x; acc.y += w * v.y;
        acc.z += w * v.z; acc.w += w * v.w;
    }
    *(float4*)&out[i4] = acc;
}

// ---------------- K4: out += A[8192x9216] * Bt^T, split-K, bf16 MFMA ----------------
// 256x256 tile, BK=32, 8 waves 2x4 (wave = 128 rows x 64 cols, 8x4 MFMA 16x16x32).
// DEPTH-3 LDS pipeline with COUNTED vmcnt across RAW barriers (T3/T4): stage(t+2)
// issued each iter; s_waitcnt vmcnt(8) waits only stage(t) — stages t+1,t+2 stay
// in flight across the barrier. No vmcnt(0) drain in the main loop.
// Race check: buffer written by stage(t+2) == buffer consumed at iter t-1, whose
// reads completed before the barrier preceding this stage issue (WAR safe);
// vmcnt(8)+barrier guarantees every wave's chunks of buf[t%3] landed (RAW safe).
// grid = 32 row-tiles * 3 col-tiles * SPLITS = 768 (1-D); atomic epilogue.
__global__ __launch_bounds__(512, 2) void gemm_attn(
    const short* __restrict__ A, const short* __restrict__ Bt,
    float* __restrict__ out) {
    __shared__ __align__(16) short As[3][256 * 32];   // 48 KiB
    __shared__ __align__(16) short Bs[3][256 * 32];   // 48 KiB

    // bijective XCD swizzle (768 % 8 == 0): XCD x owns K-chunk z == x;
    // its 32 resident blocks share one B-panel (L2) + stream the A K-chunk (L3).
    const int bid = (int)blockIdx.x;
    const int l = (bid & 7) * 96 + (bid >> 3);
    const int z = l / 96;                  // == bid & 7
    const int rem = l - z * 96;
    const int ytile = rem >> 5;            // 0..2
    const int xtile = rem & 31;            // 0..31

    const int tid = threadIdx.x;
    const int wave = tid >> 6, lane = tid & 63;
    const int row0 = xtile * 256;
    const int col0 = ytile * 256;
    const int kStart = z * KSPLIT;
    const int wr = (wave >> 2) * 128;      // 0,128
    const int wc = (wave & 3) * 64;        // 0,64,128,192

    f32x4 acc[8][4] = {};

    // staging: chunk c (16 rows x 64 B); lane -> rc=lane>>2 (row), x=lane&3 (granule)
    const int rc = lane >> 2;
    const int x = lane & 3;
    const int g = x ^ ((rc >> 1) & 3);     // XOR-swizzled 16B granule (conflict-free reads)

    int a_off[2], b_off[2], lof[2];
    #pragma unroll
    for (int j = 0; j < 2; ++j) {
        int c = wave * 2 + j;              // chunks 0..15 cover 256 rows
        a_off[j] = (row0 + c * 16 + rc) * K_ + g * 8 + kStart;
        b_off[j] = (col0 + c * 16 + rc) * K_ + g * 8 + kStart;
        lof[j] = c * 1024;                 // bytes, wave-uniform
    }

    const int fr = lane & 15;
    const int q = lane >> 4;
    const int pos = q ^ ((fr >> 1) & 3);

    // stage K-step t into LDS buffer b: 4 load instrs per wave (2 A + 2 B)
    auto stage = [&](int b, int t) {
        const int k0 = t * BK;
        #pragma unroll
        for (int j = 0; j < 2; ++j) {
            async_copy16(A + a_off[j] + k0, (char*)As[b] + lof[j]);
            async_copy16(Bt + b_off[j] + k0, (char*)Bs[b] + lof[j]);
        }
    };
    auto compute = [&](int b) {
        short8 af[8], bfr[4];
        #pragma unroll
        for (int i = 0; i < 8; ++i)
            af[i] = *(const short8*)&As[b][(wr + i * 16 + fr) * 32 + pos * 8];
        #pragma unroll
        for (int j = 0; j < 4; ++j)
            bfr[j] = *(const short8*)&Bs[b][(wc + j * 16 + fr) * 32 + pos * 8];
        #pragma unroll
        for (int i = 0; i < 8; ++i)
            #pragma unroll
            for (int j = 0; j < 4; ++j)
                acc[i][j] = __builtin_amdgcn_mfma_f32_16x16x32_bf16(
                    af[i], bfr[j], acc[i][j], 0, 0, 0);
    };

    // prologue: stage K-steps 0 and 1
    stage(0, 0);
    stage(1, 1);

    int cur = 0;
    for (int t = 0; t < NT - 2; ++t) {
        int nb = cur + 2; if (nb >= 3) nb -= 3;
        stage(nb, t + 2);
        // wait only stage(t): stages t+1, t+2 (8 instrs) stay in flight
        asm volatile("s_waitcnt vmcnt(8)" ::: "memory");
        __builtin_amdgcn_s_barrier();
        __builtin_amdgcn_sched_barrier(0);
        compute(cur);
        __builtin_amdgcn_s_barrier();
        cur = (cur == 2) ? 0 : cur + 1;
    }
    // t = NT-2: only stage(NT-1) outstanding beyond it
    asm volatile("s_waitcnt vmcnt(4)" ::: "memory");
    __builtin_amdgcn_s_barrier();
    __builtin_amdgcn_sched_barrier(0);
    compute(cur);
    __builtin_amdgcn_s_barrier();
    cur = (cur == 2) ? 0 : cur + 1;
    // t = NT-1: drain everything
    asm volatile("s_waitcnt vmcnt(0)" ::: "memory");
    __builtin_amdgcn_s_barrier();
    __builtin_amdgcn_sched_barrier(0);
    compute(cur);

    // epilogue: D row m = q*4+reg, col n = lane&15 ; atomic accumulate
    #pragma unroll
    for (int i = 0; i < 8; ++i) {
        int m = row0 + wr + i * 16 + q * 4;
        #pragma unroll
        for (int j = 0; j < 4; ++j) {
            int n = col0 + wc + j * 16 + fr;
            float* p = out + m * D_ + n;
            #pragma unroll
            for (int r = 0; r < 4; ++r)
                atomicAdd(p + r * D_, acc[i][j][r]);
        }
    }
}

extern "C" void kernel_launch(void* const* d_in, const int* in_sizes, int n_in,
                              void* d_out, int out_size, void* d_ws, size_t ws_size,
                              hipStream_t stream) {
    const float* mlp_stack  = (const float*)d_in[0];
    const float* attn_stack = (const float*)d_in[1];
    const float* mlp_mask   = (const float*)d_in[2];
    const float* attn_mask  = (const float*)d_in[3];
    const float* modal_mlp  = (const float*)d_in[4];
    const float* modal_att  = (const float*)d_in[5];
    const float* W_O        = (const float*)d_in[6];
    const float* post_bias  = (const float*)d_in[7];
    float* out = (float*)d_out;

    char* ws = (char*)d_ws;
    unsigned short* Abf = (unsigned short*)ws;                 // 150,994,944 B
    unsigned short* Btb = (unsigned short*)(ws + 150994944);   //  14,155,776 B
    float* bias = (float*)(ws + 150994944 + 14155776);         //      49,152 B

    bias_kernel<<<dim3(16, 3), 256, 0, stream>>>(mlp_mask, attn_mask, modal_mlp,
                                                 modal_att, post_bias, bias);
    transpose_wo<<<dim3(24, 288), 256, 0, stream>>>(W_O, Btb);
    conv_attn<<<36864, 256, 0, stream>>>(attn_stack, attn_mask, Abf);
    mlp_kernel<<<6144, 256, 0, stream>>>(mlp_stack, mlp_mask, bias, out);
    gemm_attn<<<768, 512, 0, stream>>>((const short*)Abf, (const short*)Btb, out);
}

// Round 3
// 941.071 us; speedup vs baseline: 1.0304x; 1.0007x over previous
//
#include <hip/hip_runtime.h>

// Shapes (fixed by the reference):
// B=16, S=512, L=12, H=12, DH=64, D=768, M=13
// attn GEMM: A rows (b,s)=8192 x K=9216, W_O = [K=9216][N=768]

#define D_ 768
#define K_ 9216
#define ROWS_ 8192   // B*S
#define SPLITS 8
#define KSPLIT (K_ / SPLITS)   // 1152
#define NKT (KSPLIT / 64)      // 18 K-tiles of 64

typedef __attribute__((ext_vector_type(8))) short short8;
typedef __attribute__((ext_vector_type(8))) unsigned short ushort8;
typedef __attribute__((ext_vector_type(4))) float f32x4;

typedef unsigned int __attribute__((address_space(1))) gu32;
typedef unsigned int __attribute__((address_space(3))) lu32;

__device__ __forceinline__ void async_copy16(const void* g, void* l) {
    __builtin_amdgcn_global_load_lds((const gu32*)g, (lu32*)l, 16, 0, 0);
}

// round-to-nearest-even f32 -> bf16 (finite inputs)
__device__ __forceinline__ unsigned short f2bf(float f) {
    union { float f; unsigned u; } a; a.f = f;
    unsigned r = a.u + 0x7FFF + ((a.u >> 16) & 1);
    return (unsigned short)(r >> 16);
}

// ---------------- K0: per-batch bias, parallel over d ----------------
__global__ __launch_bounds__(256) void bias_kernel(
    const float* __restrict__ mlp_mask, const float* __restrict__ attn_mask,
    const float* __restrict__ modal_mlp, const float* __restrict__ modal_att,
    const float* __restrict__ post_bias, float* __restrict__ bias) {
    int b = blockIdx.x;
    int d = blockIdx.y * 256 + threadIdx.x;
    float acc = 0.f;
    #pragma unroll
    for (int p = 0; p < 12; ++p) acc += post_bias[p * D_ + d];
    #pragma unroll
    for (int m = 0; m < 13; ++m)
        acc += (1.f - mlp_mask[b * 13 + m]) * modal_mlp[m * D_ + d];
    #pragma unroll 16
    for (int ph = 0; ph < 144; ++ph)
        acc += (1.f - attn_mask[b * 144 + ph]) * modal_att[ph * D_ + d];
    bias[b * D_ + d] = acc;
}

// ---------------- K1: transpose-convert W_O [9216,768] f32 -> Bt [768,9216] bf16 ----------------
__global__ __launch_bounds__(256) void transpose_wo(
    const float* __restrict__ W, unsigned short* __restrict__ Bt) {
    __shared__ float tile[32][33];
    int n0 = blockIdx.x * 32;
    int k0 = blockIdx.y * 32;
    int tx = threadIdx.x & 31, ty = threadIdx.x >> 5;
    #pragma unroll
    for (int i = 0; i < 4; ++i)
        tile[ty + 8 * i][tx] = W[(k0 + ty + 8 * i) * D_ + n0 + tx];
    __syncthreads();
    #pragma unroll
    for (int i = 0; i < 4; ++i)
        Bt[(n0 + ty + 8 * i) * K_ + k0 + tx] = f2bf(tile[tx][ty + 8 * i]);
}

// ---------------- K2: mask+convert attn_stack f32 -> A bf16, 8 elems/thread ----------------
__global__ __launch_bounds__(256) void conv_attn(
    const float* __restrict__ attn_stack, const float* __restrict__ attn_mask,
    unsigned short* __restrict__ A) {
    int i = (blockIdx.x * 256 + threadIdx.x) * 8;   // < 75.5M, fits int
    int row = i / K_;
    int k = i - row * K_;
    int b = row >> 9;
    float w = attn_mask[b * 144 + (k >> 6)];        // k 8-aligned: one (p,h) group
    float4 v0 = *(const float4*)&attn_stack[i];
    float4 v1 = *(const float4*)&attn_stack[i + 4];
    ushort8 o;
    o[0] = f2bf(v0.x * w); o[1] = f2bf(v0.y * w);
    o[2] = f2bf(v0.z * w); o[3] = f2bf(v0.w * w);
    o[4] = f2bf(v1.x * w); o[5] = f2bf(v1.y * w);
    o[6] = f2bf(v1.z * w); o[7] = f2bf(v1.w * w);
    *(ushort8*)&A[i] = o;
}

// ---------------- K3: out = bias + sum_m mlp_mask*mlp_stack ----------------
__global__ __launch_bounds__(256) void mlp_kernel(
    const float* __restrict__ mlp_stack, const float* __restrict__ mlp_mask,
    const float* __restrict__ bias, float* __restrict__ out) {
    int i4 = (blockIdx.x * 256 + threadIdx.x) * 4;
    int row = i4 / D_;
    int d = i4 - row * D_;
    int b = row >> 9;
    float4 acc = *(const float4*)&bias[b * D_ + d];
    const float* base = mlp_stack + (long)row * 13 * D_ + d;
    #pragma unroll
    for (int m = 0; m < 13; ++m) {
        float w = mlp_mask[b * 13 + m];
        float4 v = *(const float4*)&base[m * D_];
        acc.x += w * v.x; acc.y += w * v.y;
        acc.z += w * v.z; acc.w += w * v.w;
    }
    *(float4*)&out[i4] = acc;
}

// ---------------- K4: out += A[8192x9216] * Bt^T, split-K, bf16 MFMA ----------------
// m201-style phased schedule on a 256x256 tile, BK=64 window, 8 waves (2 row x 4 col;
// wave = 128 rows x 64 cols, acc 8x4 fragments). Per window: 4 sub-phases
// {ds_read frags || stage -> barrier -> lgkmcnt(0) -> setprio MFMA -> barrier}.
// All 8 global_load_lds for K-tile w+1 issue in sub-phase 0; single vmcnt(0) at
// window end => load latency hides under ~4 phases of MFMA+ds_read.
// LDS: [2 buf][2 half][128 rows][64 k] bf16, G4 row-XOR swizzle (granule ^= row&7)
// applied as inverse-swizzled GLOBAL source + swizzled reads (rule #21).
// A-frags cached across the 2 phases sharing a row-half (-33% LDS reads).
// grid = 32 row-tiles * 3 col-tiles * SPLITS = 768; atomic epilogue.
__global__ __launch_bounds__(512, 2) void gemm_attn(
    const short* __restrict__ A, const short* __restrict__ Bt,
    float* __restrict__ out) {
    __shared__ __align__(16) short Al[2][2][128 * 64];   // 64 KiB
    __shared__ __align__(16) short Bl[2][2][128 * 64];   // 64 KiB

    // bijective XCD swizzle (768 % 8 == 0): XCD x owns K-chunk z == x;
    // its blocks share a 1.8 MB B-panel (L2) and stream the A K-chunk (L3).
    const int bid = (int)blockIdx.x;
    const int l = (bid & 7) * 96 + (bid >> 3);
    const int z = l / 96;                  // == bid & 7
    const int rem = l - z * 96;
    const int ytile = rem >> 5;            // 0..2
    const int xtile = rem & 31;            // 0..31

    const int tid = threadIdx.x;
    const int wave = tid >> 6, lane = tid & 63;
    const int row0 = xtile * 256;
    const int col0 = ytile * 256;
    const int kStart = z * KSPLIT;
    const int wr = (wave >> 2) * 128;      // 0,128
    const int wc = (wave & 3) * 64;        // 0,64,128,192
    const int halfA = wave >> 2;           // which A half this wave reads
    const int halfB = (wave & 3) >> 1;     // which B half
    const int cbase = (wave & 1) * 64;     // col base within B half

    const int fr = lane & 15;
    const int qn = lane >> 4;
    const int g0 = qn ^ (fr & 7);          // swizzled 16B granule, ks=0
    const int g1 = (4 + qn) ^ (fr & 7);    // ks=1

    f32x4 acc[8][4] = {};

    // staging addressing: thread writes LDS linearly at L = tid*16 + j*8192;
    // source granule is pre-swizzled so reads with (granule ^ row&7) see A[row][k].
    int a_src[2], b_src[2], ldst[2];
    #pragma unroll
    for (int j = 0; j < 2; ++j) {
        int L = tid * 16 + j * 8192;
        int row = L >> 7;                          // row within 128-row half
        int gr = (tid & 7) ^ (row & 7);            // inverse-swizzled source granule
        a_src[j] = (row0 + row) * K_ + kStart + gr * 8;
        b_src[j] = (col0 + row) * K_ + kStart + gr * 8;
        ldst[j] = L;
    }

    // stage K-tile kt (all 4 half-tiles, 8 global_load_lds per thread)
    auto stage = [&](int kt) {
        const int buf = kt & 1;
        const int kof = kt * 64;
        #pragma unroll
        for (int h = 0; h < 2; ++h) {
            #pragma unroll
            for (int j = 0; j < 2; ++j) {
                async_copy16(A + a_src[j] + h * (128 * K_) + kof,
                             (char*)&Al[buf][h][0] + ldst[j]);
                async_copy16(Bt + b_src[j] + h * (128 * K_) + kof,
                             (char*)&Bl[buf][h][0] + ldst[j]);
            }
        }
    };

    // prologue: K-tile 0 resident before first window
    stage(0);
    asm volatile("s_waitcnt vmcnt(0)" ::: "memory");
    __builtin_amdgcn_s_barrier();
    __builtin_amdgcn_sched_barrier(0);

    for (int w = 0; w < NKT; ++w) {
        const int buf = w & 1;
        const char* Ab = (const char*)&Al[buf][halfA][0];
        const char* Bb = (const char*)&Bl[buf][halfB][0];
        short8 af[4][2];
        #pragma unroll
        for (int q = 0; q < 4; ++q) {
            const int r2 = q >> 1, c2 = q & 1;
            if (c2 == 0) {                 // A-frags cached across the c2 pair
                #pragma unroll
                for (int i = 0; i < 4; ++i) {
                    int rbyte = (r2 * 64 + i * 16 + fr) * 128;
                    af[i][0] = *(const short8*)(Ab + rbyte + g0 * 16);
                    af[i][1] = *(const short8*)(Ab + rbyte + g1 * 16);
                }
            }
            short8 bfr[2][2];
            #pragma unroll
            for (int jj = 0; jj < 2; ++jj) {
                int cbyte = (cbase + c2 * 32 + jj * 16 + fr) * 128;
                bfr[jj][0] = *(const short8*)(Bb + cbyte + g0 * 16);
                bfr[jj][1] = *(const short8*)(Bb + cbyte + g1 * 16);
            }
            if (q == 0 && w + 1 < NKT) stage(w + 1);
            __builtin_amdgcn_s_barrier();
            asm volatile("s_waitcnt lgkmcnt(0)" ::: "memory");
            __builtin_amdgcn_sched_barrier(0);
            __builtin_amdgcn_s_setprio(1);
            #pragma unroll
            for (int i = 0; i < 4; ++i) {
                #pragma unroll
                for (int jj = 0; jj < 2; ++jj) {
                    acc[r2 * 4 + i][c2 * 2 + jj] =
                        __builtin_amdgcn_mfma_f32_16x16x32_bf16(
                            af[i][0], bfr[jj][0], acc[r2 * 4 + i][c2 * 2 + jj], 0, 0, 0);
                    acc[r2 * 4 + i][c2 * 2 + jj] =
                        __builtin_amdgcn_mfma_f32_16x16x32_bf16(
                            af[i][1], bfr[jj][1], acc[r2 * 4 + i][c2 * 2 + jj], 0, 0, 0);
                }
            }
            __builtin_amdgcn_s_setprio(0);
            if (q == 3)                    // single drain per window, under compute
                asm volatile("s_waitcnt vmcnt(0)" ::: "memory");
            __builtin_amdgcn_s_barrier();
            __builtin_amdgcn_sched_barrier(0);
        }
    }

    // epilogue: D row m = qn*4+reg, col n = lane&15 ; atomic accumulate
    #pragma unroll
    for (int i = 0; i < 8; ++i) {
        int m = row0 + wr + i * 16 + qn * 4;
        #pragma unroll
        for (int j = 0; j < 4; ++j) {
            int n = col0 + wc + j * 16 + fr;
            float* p = out + m * D_ + n;
            #pragma unroll
            for (int r = 0; r < 4; ++r)
                atomicAdd(p + r * D_, acc[i][j][r]);
        }
    }
}

extern "C" void kernel_launch(void* const* d_in, const int* in_sizes, int n_in,
                              void* d_out, int out_size, void* d_ws, size_t ws_size,
                              hipStream_t stream) {
    const float* mlp_stack  = (const float*)d_in[0];
    const float* attn_stack = (const float*)d_in[1];
    const float* mlp_mask   = (const float*)d_in[2];
    const float* attn_mask  = (const float*)d_in[3];
    const float* modal_mlp  = (const float*)d_in[4];
    const float* modal_att  = (const float*)d_in[5];
    const float* W_O        = (const float*)d_in[6];
    const float* post_bias  = (const float*)d_in[7];
    float* out = (float*)d_out;

    char* ws = (char*)d_ws;
    unsigned short* Abf = (unsigned short*)ws;                 // 150,994,944 B
    unsigned short* Btb = (unsigned short*)(ws + 150994944);   //  14,155,776 B
    float* bias = (float*)(ws + 150994944 + 14155776);         //      49,152 B

    bias_kernel<<<dim3(16, 3), 256, 0, stream>>>(mlp_mask, attn_mask, modal_mlp,
                                                 modal_att, post_bias, bias);
    transpose_wo<<<dim3(24, 288), 256, 0, stream>>>(W_O, Btb);
    conv_attn<<<36864, 256, 0, stream>>>(attn_stack, attn_mask, Abf);
    mlp_kernel<<<6144, 256, 0, stream>>>(mlp_stack, mlp_mask, bias, out);
    gemm_attn<<<768, 512, 0, stream>>>((const short*)Abf, (const short*)Btb, out);
}